// Round 7
// baseline (915.080 us; speedup 1.0000x reference)
//
#include <hip/hip_runtime.h>
#include <hip/hip_bf16.h>

#define N_NODES 50000
#define N_EDGES 1600000
#define ET (N_EDGES + N_NODES)
#define G_GRAPHS 128
#define LOG2E 1.4426950408889634f

typedef unsigned short ushort8v __attribute__((ext_vector_type(8)));
typedef unsigned short ushort4v __attribute__((ext_vector_type(4)));

__device__ __forceinline__ float bf2f(unsigned short u)
{
    return __uint_as_float(((unsigned int)u) << 16);
}
__device__ __forceinline__ unsigned short f2bf(float f)
{
    unsigned int u = __float_as_uint(f);
    u = (u + 0x7FFFu + ((u >> 16) & 1u)) >> 16;
    return (unsigned short)u;
}
__device__ __forceinline__ float exp2fast(float x) { return __builtin_amdgcn_exp2f(x); }
// leaky_relu(x) = max(x, 0.2x)  (valid for slope<1)
__device__ __forceinline__ float lrelu(float x) { return fmaxf(x, 0.2f * x); }

// ---------------- small utility kernels ----------------

__global__ void ea_sum_kernel(const float* __restrict__ ea, float* __restrict__ out, int n)
{
    float s = 0.f;
    for (int i = blockIdx.x * blockDim.x + threadIdx.x; i < n; i += gridDim.x * blockDim.x)
        s += ea[i];
    #pragma unroll
    for (int off = 32; off; off >>= 1) s += __shfl_xor(s, off);
    if ((threadIdx.x & 63) == 0) atomicAdd(out, s);
}

// ws scalars layout: [0]=ea_sum [1]=ea_mean [2..5]=c1[4]*log2e [6]=c2*log2e
__global__ void scalars_kernel(float* __restrict__ ws,
                               const float* __restrict__ We1, const float* __restrict__ ae1,
                               const float* __restrict__ We2, const float* __restrict__ ae2)
{
    if (threadIdx.x == 0 && blockIdx.x == 0) {
        ws[1] = ws[0] / (float)N_EDGES;
        for (int h = 0; h < 4; ++h) {
            float c = 0.f;
            for (int o = 0; o < 64; ++o) c += We1[h * 64 + o] * ae1[h * 64 + o];
            ws[2 + h] = c * LOG2E;
        }
        float c2 = 0.f;
        for (int o = 0; o < 64; ++o) c2 += We2[o] * ae2[o];
        ws[6] = c2 * LOG2E;
    }
}

__global__ void deg_kernel(const int* __restrict__ ei, int* __restrict__ deg)
{
    for (int e = blockIdx.x * blockDim.x + threadIdx.x; e < ET; e += gridDim.x * blockDim.x) {
        int dst = (e < N_EDGES) ? ei[N_EDGES + e] : (e - N_EDGES);
        atomicAdd(&deg[dst], 1);
    }
}

__global__ __launch_bounds__(1024) void scan_kernel(const int* __restrict__ deg,
                                                    int* __restrict__ rowstart,
                                                    int* __restrict__ cursor)
{
    __shared__ int ssum[1024];
    const int C = (N_NODES + 1023) / 1024;   // 49
    int tid = threadIdx.x;
    int c0 = tid * C, c1 = min(c0 + C, N_NODES);
    int s = 0;
    for (int i = c0; i < c1; ++i) s += deg[i];
    ssum[tid] = s;
    __syncthreads();
    for (int off = 1; off < 1024; off <<= 1) {
        int v = (tid >= off) ? ssum[tid - off] : 0;
        __syncthreads();
        ssum[tid] += v;
        __syncthreads();
    }
    int run = ssum[tid] - s;  // exclusive prefix
    for (int i = c0; i < c1; ++i) { rowstart[i] = run; cursor[i] = run; run += deg[i]; }
    if (tid == 1023) rowstart[N_NODES] = ET;
}

__global__ void fill_kernel(const int* __restrict__ ei, const float* __restrict__ ea,
                            const float* __restrict__ ws, int* __restrict__ cursor,
                            int* __restrict__ csr_src, float* __restrict__ csr_ea)
{
    float mean = ws[1];
    for (int e = blockIdx.x * blockDim.x + threadIdx.x; e < ET; e += gridDim.x * blockDim.x) {
        int src, dst; float v;
        if (e < N_EDGES) { src = ei[e]; dst = ei[N_EDGES + e]; v = ea[e]; }
        else             { src = dst = e - N_EDGES; v = mean; }
        int pos = atomicAdd(&cursor[dst], 1);
        csr_src[pos] = src;
        csr_ea[pos]  = v;
    }
}

// ---------------- per-row src sort (perf-only: improves L2 locality of gathers) ----------------
// One wave per row. Rank sort via shuffle broadcast; reads csr, writes csr2 (no in-place hazard).
// Rows longer than 128 are copied unsorted (correctness unaffected).

__global__ __launch_bounds__(256) void sortrow_kernel(const int* __restrict__ rowstart,
                                                      const int* __restrict__ csr_src,
                                                      const float* __restrict__ csr_ea,
                                                      int* __restrict__ csr_src2,
                                                      float* __restrict__ csr_ea2)
{
    int wid  = (blockIdx.x * blockDim.x + threadIdx.x) >> 6;
    int lane = threadIdx.x & 63;
    if (wid >= N_NODES) return;
    int rs = rowstart[wid], re = rowstart[wid + 1];
    int n = re - rs;
    if (n > 128) {
        for (int p = rs + lane; p < re; p += 64) { csr_src2[p] = csr_src[p]; csr_ea2[p] = csr_ea[p]; }
        return;
    }
    bool v0 = lane < n, v1 = 64 + lane < n;
    int   s0 = 0, s1 = 0;
    float a0 = 0.f, a1 = 0.f;
    if (v0) { s0 = csr_src[rs + lane];      a0 = csr_ea[rs + lane]; }
    if (v1) { s1 = csr_src[rs + 64 + lane]; a1 = csr_ea[rs + 64 + lane]; }
    unsigned long long k0 = v0 ? ((((unsigned long long)(unsigned)s0) << 32) | (unsigned)lane)        : ~0ull;
    unsigned long long k1 = v1 ? ((((unsigned long long)(unsigned)s1) << 32) | (unsigned)(64 + lane)) : ~0ull;
    int r0 = 0, r1 = 0;
    #pragma unroll 8
    for (int l = 0; l < 64; ++l) {
        unsigned long long b0 = __shfl(k0, l);
        unsigned long long b1 = __shfl(k1, l);
        r0 += (b0 < k0) + (b1 < k0);
        r1 += (b0 < k1) + (b1 < k1);
    }
    if (v0) { csr_src2[rs + r0] = s0; csr_ea2[rs + r0] = a0; }
    if (v1) { csr_src2[rs + r1] = s1; csr_ea2[rs + r1] = a1; }
}

// graph start offsets in the sorted batch_idx (129 entries)
__global__ void gstart_kernel(const int* __restrict__ bidx, int* __restrict__ gstart)
{
    int g = blockIdx.x * blockDim.x + threadIdx.x;
    if (g > G_GRAPHS) return;
    int lo = 0, hi = N_NODES;
    while (lo < hi) { int mid = (lo + hi) >> 1; if (bidx[mid] < g) lo = mid + 1; else hi = mid; }
    gstart[g] = lo;
}

// ---------------- f32 tiled GEMM: C[M,NC] = A[M,K] @ B[K,NC] ----------------
template <int BK, bool BF16OUT>
__global__ __launch_bounds__(256) void gemm_tile(const float* __restrict__ A,
                                                 const float* __restrict__ B,
                                                 void* __restrict__ Cv,
                                                 int M, int K, int NC)
{
    __shared__ __align__(16) float As[BK][64];
    __shared__ __align__(16) float Bs[BK][64];
    int tid = threadIdx.x;
    int tx = tid & 15, ty = tid >> 4;
    int rowBase = blockIdx.y * 64;
    int colBase = blockIdx.x * 64;
    float acc[4][4] = {};
    for (int k0 = 0; k0 < K; k0 += BK) {
        {
            int r  = tid >> 2;
            int kq = (tid & 3) * 4;
            int grow = rowBase + r;
            float4 v = make_float4(0.f, 0.f, 0.f, 0.f);
            if (grow < M) v = *(const float4*)&A[(size_t)grow * K + k0 + kq];
            As[kq + 0][r] = v.x; As[kq + 1][r] = v.y;
            As[kq + 2][r] = v.z; As[kq + 3][r] = v.w;
        }
        {
            int kk = tid >> 4;
            int c  = (tid & 15) * 4;
            float4 v = *(const float4*)&B[(size_t)(k0 + kk) * NC + colBase + c];
            *(float4*)&Bs[kk][c] = v;
        }
        __syncthreads();
        #pragma unroll
        for (int k = 0; k < BK; ++k) {
            float4 a4 = *(const float4*)&As[k][ty * 4];
            float4 b4 = *(const float4*)&Bs[k][tx * 4];
            float aa[4] = {a4.x, a4.y, a4.z, a4.w};
            float bb[4] = {b4.x, b4.y, b4.z, b4.w};
            #pragma unroll
            for (int i = 0; i < 4; ++i)
                #pragma unroll
                for (int j = 0; j < 4; ++j)
                    acc[i][j] = fmaf(aa[i], bb[j], acc[i][j]);
        }
        __syncthreads();
    }
    #pragma unroll
    for (int i = 0; i < 4; ++i) {
        int grow = rowBase + ty * 4 + i;
        if (grow < M) {
            if constexpr (BF16OUT) {
                ushort4v o;
                o[0] = f2bf(acc[i][0]); o[1] = f2bf(acc[i][1]);
                o[2] = f2bf(acc[i][2]); o[3] = f2bf(acc[i][3]);
                *(ushort4v*)&((unsigned short*)Cv)[(size_t)grow * NC + colBase + tx * 4] = o;
            } else {
                float4 o = make_float4(acc[i][0], acc[i][1], acc[i][2], acc[i][3]);
                *(float4*)&((float*)Cv)[(size_t)grow * NC + colBase + tx * 4] = o;
            }
        }
    }
}

// ---------------- per-node alpha projections (bf16 features), pre-scaled by log2e ----------------

__global__ __launch_bounds__(256) void alphas1_kernel(const unsigned short* __restrict__ h1bf,
                                                      const float* __restrict__ as1,
                                                      const float* __restrict__ ad1,
                                                      float* __restrict__ asrc,
                                                      float* __restrict__ adst)
{
    int wid  = (blockIdx.x * blockDim.x + threadIdx.x) >> 6;
    int lane = threadIdx.x & 63;
    if (wid >= N_NODES) return;
    const unsigned short* hr = h1bf + (size_t)wid * 256;
    float sa[4], da[4];
    #pragma unroll
    for (int j = 0; j < 4; ++j) {
        float v = bf2f(hr[j * 64 + lane]);
        sa[j] = v * as1[j * 64 + lane];
        da[j] = v * ad1[j * 64 + lane];
    }
    #pragma unroll
    for (int off = 32; off; off >>= 1)
        #pragma unroll
        for (int j = 0; j < 4; ++j) {
            sa[j] += __shfl_xor(sa[j], off);
            da[j] += __shfl_xor(da[j], off);
        }
    if (lane == 0)
        #pragma unroll
        for (int j = 0; j < 4; ++j) {
            asrc[(size_t)wid * 4 + j] = sa[j] * LOG2E;
            adst[(size_t)wid * 4 + j] = da[j] * LOG2E;
        }
}

__global__ __launch_bounds__(256) void alphas2_kernel(const unsigned short* __restrict__ h2bf,
                                                      const float* __restrict__ as2,
                                                      const float* __restrict__ ad2,
                                                      float* __restrict__ asrc,
                                                      float* __restrict__ adst)
{
    int wid  = (blockIdx.x * blockDim.x + threadIdx.x) >> 6;
    int lane = threadIdx.x & 63;
    if (wid >= N_NODES) return;
    float v  = bf2f(h2bf[(size_t)wid * 64 + lane]);
    float sa = v * as2[lane];
    float da = v * ad2[lane];
    #pragma unroll
    for (int off = 32; off; off >>= 1) {
        sa += __shfl_xor(sa, off);
        da += __shfl_xor(da, off);
    }
    if (lane == 0) { asrc[wid] = sa * LOG2E; adst[wid] = da * LOG2E; }
}

// ---------------- layer 1: no-max softmax (exp2 domain) + aggregation ----------------
// phase 2: 2 lane-groups x 32 lanes; lane covers 8 channels; 8 loads = 16 edges/iter.

__global__ __launch_bounds__(256) void agg1_kernel(const int* __restrict__ rowstart,
                                                   const int* __restrict__ csr_src,
                                                   const float* __restrict__ csr_ea,
                                                   const float* __restrict__ asrc,
                                                   const float* __restrict__ adst,
                                                   const float* __restrict__ ws,
                                                   const unsigned short* __restrict__ h1bf,
                                                   const float* __restrict__ b1,
                                                   float* __restrict__ h1r)
{
    int wid  = (blockIdx.x * blockDim.x + threadIdx.x) >> 6;
    int lane = threadIdx.x & 63;
    if (wid >= N_NODES) return;
    int rs = rowstart[wid], re = rowstart[wid + 1];
    float c[4], ad[4];
    #pragma unroll
    for (int h = 0; h < 4; ++h) { c[h] = ws[2 + h]; ad[h] = adst[(size_t)wid * 4 + h]; }

    // phase 1: denominator sum per head (no max subtraction), edges strided across lanes
    float s[4] = {0.f, 0.f, 0.f, 0.f};
    for (int p = rs + lane; p < re; p += 64) {
        int src  = csr_src[p];
        float ev = csr_ea[p];
        float4 av = *(const float4*)&asrc[(size_t)src * 4];
        s[0] += exp2fast(lrelu(fmaf(ev, c[0], av.x + ad[0])));
        s[1] += exp2fast(lrelu(fmaf(ev, c[1], av.y + ad[1])));
        s[2] += exp2fast(lrelu(fmaf(ev, c[2], av.z + ad[2])));
        s[3] += exp2fast(lrelu(fmaf(ev, c[3], av.w + ad[3])));
    }
    #pragma unroll
    for (int off = 1; off < 64; off <<= 1)
        #pragma unroll
        for (int h = 0; h < 4; ++h)
            s[h] += __shfl_xor(s[h], off);
    float inv[4];
    #pragma unroll
    for (int h = 0; h < 4; ++h) inv[h] = 1.0f / (s[h] + 1e-16f);

    // phase 2
    int g   = lane >> 5;        // edge sub-slot (0..1)
    int sub = lane & 31;        // channel block: channels sub*8 .. sub*8+7
    int hh  = sub >> 3;         // head of this lane's channels
    float ad_s = hh < 2 ? (hh == 0 ? ad[0] : ad[1]) : (hh == 2 ? ad[2] : ad[3]);
    float c_s  = hh < 2 ? (hh == 0 ? c[0]  : c[1])  : (hh == 2 ? c[2]  : c[3]);
    float i_s  = hh < 2 ? (hh == 0 ? inv[0]: inv[1]): (hh == 2 ? inv[2]: inv[3]);

    float acc[8] = {};
    for (int p = rs; p < re; p += 16) {
        #pragma unroll
        for (int k = 0; k < 8; ++k) {
            int pe = p + 2 * k + g;
            bool act = pe < re;
            int idx = act ? pe : re - 1;
            int src  = csr_src[idx];
            float ev = csr_ea[idx];
            ushort8v r = *(const ushort8v*)&h1bf[(size_t)src * 256 + sub * 8];
            float al = lrelu(fmaf(ev, c_s, asrc[(size_t)src * 4 + hh] + ad_s));
            float wgt = act ? exp2fast(al) * i_s : 0.f;
            #pragma unroll
            for (int j = 0; j < 8; ++j)
                acc[j] = fmaf(bf2f(r[j]), wgt, acc[j]);
        }
    }
    #pragma unroll
    for (int j = 0; j < 8; ++j) acc[j] += __shfl_xor(acc[j], 32);
    if (g == 0) {
        float* o = h1r + (size_t)wid * 256 + sub * 8;
        float4 ba = *(const float4*)&b1[sub * 8];
        float4 bb = *(const float4*)&b1[sub * 8 + 4];
        float4 o0, o1;
        o0.x = fmaxf(acc[0] + ba.x, 0.f); o0.y = fmaxf(acc[1] + ba.y, 0.f);
        o0.z = fmaxf(acc[2] + ba.z, 0.f); o0.w = fmaxf(acc[3] + ba.w, 0.f);
        o1.x = fmaxf(acc[4] + bb.x, 0.f); o1.y = fmaxf(acc[5] + bb.y, 0.f);
        o1.z = fmaxf(acc[6] + bb.z, 0.f); o1.w = fmaxf(acc[7] + bb.w, 0.f);
        *(float4*)&o[0] = o0;
        *(float4*)&o[4] = o1;
    }
}

// ---------------- layer 2 (H=1): no-max softmax + aggregation, direct store ----------------
// phase 2: 8 lane-groups x 8 lanes; lane covers 8 channels; 4 loads = 32 edges/iter.

__global__ __launch_bounds__(256) void agg2_kernel(const int* __restrict__ rowstart,
                                                   const int* __restrict__ csr_src,
                                                   const float* __restrict__ csr_ea,
                                                   const float* __restrict__ asrc,
                                                   const float* __restrict__ adst,
                                                   const float* __restrict__ ws,
                                                   const unsigned short* __restrict__ h2bf,
                                                   const float* __restrict__ b2,
                                                   float* __restrict__ h2out)
{
    int wid  = (blockIdx.x * blockDim.x + threadIdx.x) >> 6;
    int lane = threadIdx.x & 63;
    if (wid >= N_NODES) return;
    int rs = rowstart[wid], re = rowstart[wid + 1];
    float c2 = ws[6];
    float ad = adst[wid];
    float s = 0.f;
    for (int p = rs + lane; p < re; p += 64) {
        int src  = csr_src[p];
        float ev = csr_ea[p];
        s += exp2fast(lrelu(fmaf(ev, c2, asrc[src] + ad)));
    }
    #pragma unroll
    for (int off = 1; off < 64; off <<= 1)
        s += __shfl_xor(s, off);
    float inv = 1.0f / (s + 1e-16f);

    int g   = lane >> 3;   // edge sub-slot (0..7)
    int sub = lane & 7;    // channel block: channels sub*8 .. sub*8+7
    float acc[8] = {};
    for (int p = rs; p < re; p += 32) {
        #pragma unroll
        for (int k = 0; k < 4; ++k) {
            int pe = p + 8 * k + g;
            bool act = pe < re;
            int idx = act ? pe : re - 1;
            int src  = csr_src[idx];
            float ev = csr_ea[idx];
            ushort8v r = *(const ushort8v*)&h2bf[(size_t)src * 64 + sub * 8];
            float al = lrelu(fmaf(ev, c2, asrc[src] + ad));
            float wgt = act ? exp2fast(al) * inv : 0.f;
            #pragma unroll
            for (int j = 0; j < 8; ++j)
                acc[j] = fmaf(bf2f(r[j]), wgt, acc[j]);
        }
    }
    #pragma unroll
    for (int j = 0; j < 8; ++j) {
        acc[j] += __shfl_xor(acc[j], 8);
        acc[j] += __shfl_xor(acc[j], 16);
        acc[j] += __shfl_xor(acc[j], 32);
    }
    if (g == 0) {
        float4 ba = *(const float4*)&b2[sub * 8];
        float4 bb = *(const float4*)&b2[sub * 8 + 4];
        float4 o0, o1;
        o0.x = acc[0] + ba.x; o0.y = acc[1] + ba.y;
        o0.z = acc[2] + ba.z; o0.w = acc[3] + ba.w;
        o1.x = acc[4] + bb.x; o1.y = acc[5] + bb.y;
        o1.z = acc[6] + bb.z; o1.w = acc[7] + bb.w;
        float* o = h2out + (size_t)wid * 64 + sub * 8;
        *(float4*)&o[0] = o0;
        *(float4*)&o[4] = o1;
    }
}

// ---------------- mean pool: one block per graph, contiguous node range ----------------

__global__ __launch_bounds__(256) void pool_kernel(const float* __restrict__ h2out,
                                                   const int* __restrict__ gstart,
                                                   float* __restrict__ pooled)
{
    __shared__ float sh[4][64];
    int g = blockIdx.x;
    int wv = threadIdx.x >> 6, lane = threadIdx.x & 63;
    int s = gstart[g], e = gstart[g + 1];
    float acc = 0.f;
    for (int n = s + wv; n < e; n += 4)
        acc += h2out[(size_t)n * 64 + lane];
    sh[wv][lane] = acc;
    __syncthreads();
    if (wv == 0) {
        float v = sh[0][lane] + sh[1][lane] + sh[2][lane] + sh[3][lane];
        float cnt = fmaxf((float)(e - s), 1.f);
        pooled[g * 64 + lane] = v / cnt;
    }
}

// ---------------- MLP head: one wave per graph ----------------

__global__ __launch_bounds__(64) void mlp_kernel(const float* __restrict__ pooled,
                                                 const float* __restrict__ Wl1,
                                                 const float* __restrict__ bl1,
                                                 const float* __restrict__ lng,
                                                 const float* __restrict__ lnb,
                                                 const float* __restrict__ Wl2,
                                                 const float* __restrict__ bl2,
                                                 float* __restrict__ out)
{
    int g = blockIdx.x, l = threadIdx.x;
    __shared__ float gs[64], zs[64];
    gs[l] = pooled[(size_t)g * 64 + l];
    __syncthreads();
    float z = bl1[l];
    for (int k = 0; k < 64; ++k) z = fmaf(gs[k], Wl1[k * 64 + l], z);
    z = fmaxf(z, 0.f);
    float sum = z;
    #pragma unroll
    for (int off = 32; off; off >>= 1) sum += __shfl_xor(sum, off);
    float mu = sum * (1.f / 64.f);
    float d  = z - mu;
    float vs = d * d;
    #pragma unroll
    for (int off = 32; off; off >>= 1) vs += __shfl_xor(vs, off);
    float var = vs * (1.f / 64.f);
    z = d * rsqrtf(var + 1e-5f) * lng[l] + lnb[l];
    zs[l] = z;
    __syncthreads();
    if (l < 16) {
        float o = bl2[l];
        for (int k = 0; k < 64; ++k) o = fmaf(zs[k], Wl2[k * 16 + l], o);
        out[g * 16 + l] = o;
    }
}

__global__ void copy_ea_kernel(const float* __restrict__ ea, float* __restrict__ out)
{
    for (int i = blockIdx.x * blockDim.x + threadIdx.x; i < N_EDGES; i += gridDim.x * blockDim.x)
        out[i] = ea[i];
}

// ---------------- launch ----------------

extern "C" void kernel_launch(void* const* d_in, const int* in_sizes, int n_in,
                              void* d_out, int out_size, void* d_ws, size_t ws_size,
                              hipStream_t stream)
{
    const float* x    = (const float*)d_in[0];
    const int*   ei   = (const int*)d_in[1];
    const float* ea   = (const float*)d_in[2];
    const int*   bidx = (const int*)d_in[3];
    const float* W1   = (const float*)d_in[4];
    const float* as1  = (const float*)d_in[5];
    const float* ad1  = (const float*)d_in[6];
    const float* We1  = (const float*)d_in[7];
    const float* ae1  = (const float*)d_in[8];
    const float* b1   = (const float*)d_in[9];
    const float* W2   = (const float*)d_in[10];
    const float* as2  = (const float*)d_in[11];
    const float* ad2  = (const float*)d_in[12];
    const float* We2  = (const float*)d_in[13];
    const float* ae2  = (const float*)d_in[14];
    const float* b2   = (const float*)d_in[15];
    const float* Wl1  = (const float*)d_in[16];
    const float* bl1  = (const float*)d_in[17];
    const float* lng  = (const float*)d_in[18];
    const float* lnb  = (const float*)d_in[19];
    const float* Wl2  = (const float*)d_in[20];
    const float* bl2  = (const float*)d_in[21];
    float* out = (float*)d_out;

    char* w = (char*)d_ws;
    float* scalars  = (float*)(w + 0);            // 64 B
    int*   deg      = (int*)  (w + 64);           // 200000 B
    const size_t zbytes = 200064;
    int*   rowstart = (int*)  (w + 200064);       // 200004 B (pad to 400128)
    int*   cursor   = (int*)  (w + 400128);       // 200000 B
    int*   gstart   = (int*)  (w + 600128);       // 516 B (pad to 600704)
    int*   csr_src  = (int*)  (w + 600704);       // 6.6 MB
    float* csr_ea   = (float*)(w + 7200704);      // 6.6 MB
    float* asrc1    = (float*)(w + 13800704);     // 800 KB
    float* adst1    = (float*)(w + 14600704);     // 800 KB
    float* asrc2    = (float*)(w + 15400704);     // 200 KB
    float* adst2    = (float*)(w + 15600704);     // 200 KB
    float* pooled   = (float*)(w + 15800704);     // 32 KB
    unsigned short* h1bf = (unsigned short*)(w + 15833472);   // 25.6 MB
    float* h1r      = (float*)(w + 41433472);     // 51.2 MB
    unsigned short* h2bf = (unsigned short*)(w + 92633472);   // 6.4 MB
    float* h2out    = (float*)(w + 99033472);     // 12.8 MB
    int*   csr_src2 = (int*)  (w + 111833472);    // 6.6 MB
    float* csr_ea2  = (float*)(w + 118433472);    // 6.6 MB -> ends 125033472

    hipMemsetAsync(d_ws, 0, zbytes, stream);
    ea_sum_kernel<<<512, 256, 0, stream>>>(ea, scalars, N_EDGES);
    scalars_kernel<<<1, 64, 0, stream>>>(scalars, We1, ae1, We2, ae2);
    deg_kernel<<<1024, 256, 0, stream>>>(ei, deg);
    scan_kernel<<<1, 1024, 0, stream>>>(deg, rowstart, cursor);
    fill_kernel<<<1024, 256, 0, stream>>>(ei, ea, scalars, cursor, csr_src, csr_ea);
    sortrow_kernel<<<12500, 256, 0, stream>>>(rowstart, csr_src, csr_ea, csr_src2, csr_ea2);
    gstart_kernel<<<1, 192, 0, stream>>>(bidx, gstart);

    { dim3 g(4, 782);  gemm_tile<16, true><<<g, 256, 0, stream>>>(x, W1, h1bf, N_NODES, 128, 256); }
    alphas1_kernel<<<12500, 256, 0, stream>>>(h1bf, as1, ad1, asrc1, adst1);
    agg1_kernel<<<12500, 256, 0, stream>>>(rowstart, csr_src2, csr_ea2, asrc1, adst1,
                                           scalars, h1bf, b1, h1r);
    { dim3 g(1, 782);  gemm_tile<16, true><<<g, 256, 0, stream>>>(h1r, W2, h2bf, N_NODES, 256, 64); }
    alphas2_kernel<<<12500, 256, 0, stream>>>(h2bf, as2, ad2, asrc2, adst2);
    agg2_kernel<<<12500, 256, 0, stream>>>(rowstart, csr_src2, csr_ea2, asrc2, adst2,
                                           scalars, h2bf, b2, h2out);
    pool_kernel<<<G_GRAPHS, 256, 0, stream>>>(h2out, gstart, pooled);
    mlp_kernel<<<G_GRAPHS, 64, 0, stream>>>(pooled, Wl1, bl1, lng, lnb, Wl2, bl2, out);
    copy_ea_kernel<<<2048, 256, 0, stream>>>(ea, out + 2048);
}

// Round 8
// 771.368 us; speedup vs baseline: 1.1863x; 1.1863x over previous
//
#include <hip/hip_runtime.h>
#include <hip/hip_bf16.h>

#define N_NODES 50000
#define N_PAD 50048           // padded rows for MFMA tiles (multiple of 64)
#define N_EDGES 1600000
#define ET (N_EDGES + N_NODES)
#define G_GRAPHS 128
#define LOG2E 1.4426950408889634f

typedef unsigned short ushort8v __attribute__((ext_vector_type(8)));
typedef unsigned short ushort4v __attribute__((ext_vector_type(4)));
typedef short bf16x8 __attribute__((ext_vector_type(8)));
typedef float f32x4 __attribute__((ext_vector_type(4)));

__device__ __forceinline__ float bf2f(unsigned short u)
{
    return __uint_as_float(((unsigned int)u) << 16);
}
__device__ __forceinline__ unsigned short f2bf(float f)
{
    unsigned int u = __float_as_uint(f);
    u = (u + 0x7FFFu + ((u >> 16) & 1u)) >> 16;
    return (unsigned short)u;
}
__device__ __forceinline__ float exp2fast(float x) { return __builtin_amdgcn_exp2f(x); }
__device__ __forceinline__ float lrelu(float x) { return fmaxf(x, 0.2f * x); }

// ---------------- small utility kernels ----------------

__global__ void ea_sum_kernel(const float* __restrict__ ea, float* __restrict__ out, int n)
{
    float s = 0.f;
    for (int i = blockIdx.x * blockDim.x + threadIdx.x; i < n; i += gridDim.x * blockDim.x)
        s += ea[i];
    #pragma unroll
    for (int off = 32; off; off >>= 1) s += __shfl_xor(s, off);
    if ((threadIdx.x & 63) == 0) atomicAdd(out, s);
}

// ws scalars layout: [0]=ea_sum [1]=ea_mean [2..5]=c1[4]*log2e [6]=c2*log2e
__global__ void scalars_kernel(float* __restrict__ ws,
                               const float* __restrict__ We1, const float* __restrict__ ae1,
                               const float* __restrict__ We2, const float* __restrict__ ae2)
{
    if (threadIdx.x == 0 && blockIdx.x == 0) {
        ws[1] = ws[0] / (float)N_EDGES;
        for (int h = 0; h < 4; ++h) {
            float c = 0.f;
            for (int o = 0; o < 64; ++o) c += We1[h * 64 + o] * ae1[h * 64 + o];
            ws[2 + h] = c * LOG2E;
        }
        float c2 = 0.f;
        for (int o = 0; o < 64; ++o) c2 += We2[o] * ae2[o];
        ws[6] = c2 * LOG2E;
    }
}

__global__ void deg_kernel(const int* __restrict__ ei, int* __restrict__ deg)
{
    for (int e = blockIdx.x * blockDim.x + threadIdx.x; e < ET; e += gridDim.x * blockDim.x) {
        int dst = (e < N_EDGES) ? ei[N_EDGES + e] : (e - N_EDGES);
        atomicAdd(&deg[dst], 1);
    }
}

__global__ __launch_bounds__(1024) void scan_kernel(const int* __restrict__ deg,
                                                    int* __restrict__ rowstart,
                                                    int* __restrict__ cursor)
{
    __shared__ int ssum[1024];
    const int C = (N_NODES + 1023) / 1024;   // 49
    int tid = threadIdx.x;
    int c0 = tid * C, c1 = min(c0 + C, N_NODES);
    int s = 0;
    for (int i = c0; i < c1; ++i) s += deg[i];
    ssum[tid] = s;
    __syncthreads();
    for (int off = 1; off < 1024; off <<= 1) {
        int v = (tid >= off) ? ssum[tid - off] : 0;
        __syncthreads();
        ssum[tid] += v;
        __syncthreads();
    }
    int run = ssum[tid] - s;  // exclusive prefix
    for (int i = c0; i < c1; ++i) { rowstart[i] = run; cursor[i] = run; run += deg[i]; }
    if (tid == 1023) rowstart[N_NODES] = ET;
}

__global__ void fill_kernel(const int* __restrict__ ei, const float* __restrict__ ea,
                            const float* __restrict__ ws, int* __restrict__ cursor,
                            int* __restrict__ csr_src, float* __restrict__ csr_ea)
{
    float mean = ws[1];
    for (int e = blockIdx.x * blockDim.x + threadIdx.x; e < ET; e += gridDim.x * blockDim.x) {
        int src, dst; float v;
        if (e < N_EDGES) { src = ei[e]; dst = ei[N_EDGES + e]; v = ea[e]; }
        else             { src = dst = e - N_EDGES; v = mean; }
        int pos = atomicAdd(&cursor[dst], 1);
        csr_src[pos] = src;
        csr_ea[pos]  = v;
    }
}

// graph start offsets in the sorted batch_idx (129 entries)
__global__ void gstart_kernel(const int* __restrict__ bidx, int* __restrict__ gstart)
{
    int g = blockIdx.x * blockDim.x + threadIdx.x;
    if (g > G_GRAPHS) return;
    int lo = 0, hi = N_NODES;
    while (lo < hi) { int mid = (lo + hi) >> 1; if (bidx[mid] < g) lo = mid + 1; else hi = mid; }
    gstart[g] = lo;
}

// transpose+cast weights: W1[128][256]->W1t[256][128] bf16; W2[256][64]->W2t[64][256] bf16
__global__ void wcast_kernel(const float* __restrict__ W1, const float* __restrict__ W2,
                             unsigned short* __restrict__ W1t, unsigned short* __restrict__ W2t)
{
    int i = blockIdx.x * blockDim.x + threadIdx.x;
    if (i < 128 * 256) { int k = i >> 8, c = i & 255; W1t[c * 128 + k] = f2bf(W1[i]); }
    if (i < 256 * 64)  { int k = i >> 6, c = i & 63;  W2t[c * 256 + k] = f2bf(W2[i]); }
}

// ---------------- MFMA bf16 GEMM: C[M,NC](bf16) = A[M,K] @ Wt^T ----------------
// Wt is NC x K (pre-transposed). D^T-form: mfma(A'=Wt-frag, B'=A-frag) -> D'[nc,m].
// Layout (16x16x32): A'row = lane&15 (=nc), B'col = lane&15 (=m), k = (lane>>4)*8+i.
// C/D: col = lane&15 (=m), row = (lane>>4)*4+reg (=nc). One block = 64 rows, all NC cols.
template <int K, int NCB, bool A_F32>
__global__ __launch_bounds__(256) void gemm_mfma(const void* __restrict__ Av,
                                                 const unsigned short* __restrict__ Wt,
                                                 unsigned short* __restrict__ C,
                                                 int M)
{
    const int NC = NCB * 16;
    int wave = threadIdx.x >> 6, lane = threadIdx.x & 63;
    int l16 = lane & 15, lk = lane >> 4;
    int m = blockIdx.x * 64 + wave * 16 + l16;
    if (m >= M) m = M - 1;                 // clamp: tail lanes duplicate row M-1 (benign)
    f32x4 acc[NCB] = {};
    #pragma unroll
    for (int k0 = 0; k0 < K; k0 += 32) {
        int kk = k0 + lk * 8;
        bf16x8 af;
        if constexpr (A_F32) {
            const float* A = (const float*)Av;
            float4 u0 = *(const float4*)&A[(size_t)m * K + kk];
            float4 u1 = *(const float4*)&A[(size_t)m * K + kk + 4];
            af[0] = (short)f2bf(u0.x); af[1] = (short)f2bf(u0.y);
            af[2] = (short)f2bf(u0.z); af[3] = (short)f2bf(u0.w);
            af[4] = (short)f2bf(u1.x); af[5] = (short)f2bf(u1.y);
            af[6] = (short)f2bf(u1.z); af[7] = (short)f2bf(u1.w);
        } else {
            af = *(const bf16x8*)&((const unsigned short*)Av)[(size_t)m * K + kk];
        }
        #pragma unroll
        for (int cb = 0; cb < NCB; ++cb) {
            bf16x8 wf = *(const bf16x8*)&Wt[(size_t)(cb * 16 + l16) * K + kk];
            acc[cb] = __builtin_amdgcn_mfma_f32_16x16x32_bf16(wf, af, acc[cb], 0, 0, 0);
        }
    }
    #pragma unroll
    for (int cb = 0; cb < NCB; ++cb) {
        ushort4v o;
        o[0] = f2bf(acc[cb][0]); o[1] = f2bf(acc[cb][1]);
        o[2] = f2bf(acc[cb][2]); o[3] = f2bf(acc[cb][3]);
        *(ushort4v*)&C[(size_t)m * NC + cb * 16 + lk * 4] = o;
    }
}

// ---------------- per-node alpha projections (bf16 features), pre-scaled by log2e ----------------

__global__ __launch_bounds__(256) void alphas1_kernel(const unsigned short* __restrict__ h1bf,
                                                      const float* __restrict__ as1,
                                                      const float* __restrict__ ad1,
                                                      float* __restrict__ asrc,
                                                      float* __restrict__ adst)
{
    int wid  = (blockIdx.x * blockDim.x + threadIdx.x) >> 6;
    int lane = threadIdx.x & 63;
    if (wid >= N_NODES) return;
    const unsigned short* hr = h1bf + (size_t)wid * 256;
    float sa[4], da[4];
    #pragma unroll
    for (int j = 0; j < 4; ++j) {
        float v = bf2f(hr[j * 64 + lane]);
        sa[j] = v * as1[j * 64 + lane];
        da[j] = v * ad1[j * 64 + lane];
    }
    #pragma unroll
    for (int off = 32; off; off >>= 1)
        #pragma unroll
        for (int j = 0; j < 4; ++j) {
            sa[j] += __shfl_xor(sa[j], off);
            da[j] += __shfl_xor(da[j], off);
        }
    if (lane == 0)
        #pragma unroll
        for (int j = 0; j < 4; ++j) {
            asrc[(size_t)wid * 4 + j] = sa[j] * LOG2E;
            adst[(size_t)wid * 4 + j] = da[j] * LOG2E;
        }
}

__global__ __launch_bounds__(256) void alphas2_kernel(const unsigned short* __restrict__ h2bf,
                                                      const float* __restrict__ as2,
                                                      const float* __restrict__ ad2,
                                                      float* __restrict__ asrc,
                                                      float* __restrict__ adst)
{
    int wid  = (blockIdx.x * blockDim.x + threadIdx.x) >> 6;
    int lane = threadIdx.x & 63;
    if (wid >= N_NODES) return;
    float v  = bf2f(h2bf[(size_t)wid * 64 + lane]);
    float sa = v * as2[lane];
    float da = v * ad2[lane];
    #pragma unroll
    for (int off = 32; off; off >>= 1) {
        sa += __shfl_xor(sa, off);
        da += __shfl_xor(da, off);
    }
    if (lane == 0) { asrc[wid] = sa * LOG2E; adst[wid] = da * LOG2E; }
}

// ---------------- layer 1: no-max softmax (exp2 domain) + aggregation ----------------
// phase 2: 2 lane-groups x 32 lanes; lane covers 8 channels; 8 loads = 16 edges/iter.
// Output h1r written as bf16 (feeds MFMA gemm2).

__global__ __launch_bounds__(256) void agg1_kernel(const int* __restrict__ rowstart,
                                                   const int* __restrict__ csr_src,
                                                   const float* __restrict__ csr_ea,
                                                   const float* __restrict__ asrc,
                                                   const float* __restrict__ adst,
                                                   const float* __restrict__ ws,
                                                   const unsigned short* __restrict__ h1bf,
                                                   const float* __restrict__ b1,
                                                   unsigned short* __restrict__ h1rbf)
{
    int wid  = (blockIdx.x * blockDim.x + threadIdx.x) >> 6;
    int lane = threadIdx.x & 63;
    if (wid >= N_NODES) return;
    int rs = rowstart[wid], re = rowstart[wid + 1];
    float c[4], ad[4];
    #pragma unroll
    for (int h = 0; h < 4; ++h) { c[h] = ws[2 + h]; ad[h] = adst[(size_t)wid * 4 + h]; }

    // phase 1: denominator sum per head (no max subtraction), edges strided across lanes
    float s[4] = {0.f, 0.f, 0.f, 0.f};
    for (int p = rs + lane; p < re; p += 64) {
        int src  = csr_src[p];
        float ev = csr_ea[p];
        float4 av = *(const float4*)&asrc[(size_t)src * 4];
        s[0] += exp2fast(lrelu(fmaf(ev, c[0], av.x + ad[0])));
        s[1] += exp2fast(lrelu(fmaf(ev, c[1], av.y + ad[1])));
        s[2] += exp2fast(lrelu(fmaf(ev, c[2], av.z + ad[2])));
        s[3] += exp2fast(lrelu(fmaf(ev, c[3], av.w + ad[3])));
    }
    #pragma unroll
    for (int off = 1; off < 64; off <<= 1)
        #pragma unroll
        for (int h = 0; h < 4; ++h)
            s[h] += __shfl_xor(s[h], off);
    float inv[4];
    #pragma unroll
    for (int h = 0; h < 4; ++h) inv[h] = 1.0f / (s[h] + 1e-16f);

    // phase 2
    int g   = lane >> 5;        // edge sub-slot (0..1)
    int sub = lane & 31;        // channel block: channels sub*8 .. sub*8+7
    int hh  = sub >> 3;         // head of this lane's channels
    float ad_s = hh < 2 ? (hh == 0 ? ad[0] : ad[1]) : (hh == 2 ? ad[2] : ad[3]);
    float c_s  = hh < 2 ? (hh == 0 ? c[0]  : c[1])  : (hh == 2 ? c[2]  : c[3]);
    float i_s  = hh < 2 ? (hh == 0 ? inv[0]: inv[1]): (hh == 2 ? inv[2]: inv[3]);

    float acc[8] = {};
    for (int p = rs; p < re; p += 16) {
        #pragma unroll
        for (int k = 0; k < 8; ++k) {
            int pe = p + 2 * k + g;
            bool act = pe < re;
            int idx = act ? pe : re - 1;
            int src  = csr_src[idx];
            float ev = csr_ea[idx];
            ushort8v r = *(const ushort8v*)&h1bf[(size_t)src * 256 + sub * 8];
            float al = lrelu(fmaf(ev, c_s, asrc[(size_t)src * 4 + hh] + ad_s));
            float wgt = act ? exp2fast(al) * i_s : 0.f;
            #pragma unroll
            for (int j = 0; j < 8; ++j)
                acc[j] = fmaf(bf2f(r[j]), wgt, acc[j]);
        }
    }
    #pragma unroll
    for (int j = 0; j < 8; ++j) acc[j] += __shfl_xor(acc[j], 32);
    if (g == 0) {
        float4 ba = *(const float4*)&b1[sub * 8];
        float4 bb = *(const float4*)&b1[sub * 8 + 4];
        ushort8v ov;
        ov[0] = f2bf(fmaxf(acc[0] + ba.x, 0.f)); ov[1] = f2bf(fmaxf(acc[1] + ba.y, 0.f));
        ov[2] = f2bf(fmaxf(acc[2] + ba.z, 0.f)); ov[3] = f2bf(fmaxf(acc[3] + ba.w, 0.f));
        ov[4] = f2bf(fmaxf(acc[4] + bb.x, 0.f)); ov[5] = f2bf(fmaxf(acc[5] + bb.y, 0.f));
        ov[6] = f2bf(fmaxf(acc[6] + bb.z, 0.f)); ov[7] = f2bf(fmaxf(acc[7] + bb.w, 0.f));
        *(ushort8v*)&h1rbf[(size_t)wid * 256 + sub * 8] = ov;
    }
}

// ---------------- layer 2 (H=1): no-max softmax + aggregation, direct store ----------------
// phase 2: 8 lane-groups x 8 lanes; lane covers 8 channels; 4 loads = 32 edges/iter.

__global__ __launch_bounds__(256) void agg2_kernel(const int* __restrict__ rowstart,
                                                   const int* __restrict__ csr_src,
                                                   const float* __restrict__ csr_ea,
                                                   const float* __restrict__ asrc,
                                                   const float* __restrict__ adst,
                                                   const float* __restrict__ ws,
                                                   const unsigned short* __restrict__ h2bf,
                                                   const float* __restrict__ b2,
                                                   float* __restrict__ h2out)
{
    int wid  = (blockIdx.x * blockDim.x + threadIdx.x) >> 6;
    int lane = threadIdx.x & 63;
    if (wid >= N_NODES) return;
    int rs = rowstart[wid], re = rowstart[wid + 1];
    float c2 = ws[6];
    float ad = adst[wid];
    float s = 0.f;
    for (int p = rs + lane; p < re; p += 64) {
        int src  = csr_src[p];
        float ev = csr_ea[p];
        s += exp2fast(lrelu(fmaf(ev, c2, asrc[src] + ad)));
    }
    #pragma unroll
    for (int off = 1; off < 64; off <<= 1)
        s += __shfl_xor(s, off);
    float inv = 1.0f / (s + 1e-16f);

    int g   = lane >> 3;   // edge sub-slot (0..7)
    int sub = lane & 7;    // channel block: channels sub*8 .. sub*8+7
    float acc[8] = {};
    for (int p = rs; p < re; p += 32) {
        #pragma unroll
        for (int k = 0; k < 4; ++k) {
            int pe = p + 8 * k + g;
            bool act = pe < re;
            int idx = act ? pe : re - 1;
            int src  = csr_src[idx];
            float ev = csr_ea[idx];
            ushort8v r = *(const ushort8v*)&h2bf[(size_t)src * 64 + sub * 8];
            float al = lrelu(fmaf(ev, c2, asrc[src] + ad));
            float wgt = act ? exp2fast(al) * inv : 0.f;
            #pragma unroll
            for (int j = 0; j < 8; ++j)
                acc[j] = fmaf(bf2f(r[j]), wgt, acc[j]);
        }
    }
    #pragma unroll
    for (int j = 0; j < 8; ++j) {
        acc[j] += __shfl_xor(acc[j], 8);
        acc[j] += __shfl_xor(acc[j], 16);
        acc[j] += __shfl_xor(acc[j], 32);
    }
    if (g == 0) {
        float4 ba = *(const float4*)&b2[sub * 8];
        float4 bb = *(const float4*)&b2[sub * 8 + 4];
        float4 o0, o1;
        o0.x = acc[0] + ba.x; o0.y = acc[1] + ba.y;
        o0.z = acc[2] + ba.z; o0.w = acc[3] + ba.w;
        o1.x = acc[4] + bb.x; o1.y = acc[5] + bb.y;
        o1.z = acc[6] + bb.z; o1.w = acc[7] + bb.w;
        float* o = h2out + (size_t)wid * 64 + sub * 8;
        *(float4*)&o[0] = o0;
        *(float4*)&o[4] = o1;
    }
}

// ---------------- mean pool: one block per graph, contiguous node range ----------------

__global__ __launch_bounds__(256) void pool_kernel(const float* __restrict__ h2out,
                                                   const int* __restrict__ gstart,
                                                   float* __restrict__ pooled)
{
    __shared__ float sh[4][64];
    int g = blockIdx.x;
    int wv = threadIdx.x >> 6, lane = threadIdx.x & 63;
    int s = gstart[g], e = gstart[g + 1];
    float acc = 0.f;
    for (int n = s + wv; n < e; n += 4)
        acc += h2out[(size_t)n * 64 + lane];
    sh[wv][lane] = acc;
    __syncthreads();
    if (wv == 0) {
        float v = sh[0][lane] + sh[1][lane] + sh[2][lane] + sh[3][lane];
        float cnt = fmaxf((float)(e - s), 1.f);
        pooled[g * 64 + lane] = v / cnt;
    }
}

// ---------------- MLP head: one wave per graph ----------------

__global__ __launch_bounds__(64) void mlp_kernel(const float* __restrict__ pooled,
                                                 const float* __restrict__ Wl1,
                                                 const float* __restrict__ bl1,
                                                 const float* __restrict__ lng,
                                                 const float* __restrict__ lnb,
                                                 const float* __restrict__ Wl2,
                                                 const float* __restrict__ bl2,
                                                 float* __restrict__ out)
{
    int g = blockIdx.x, l = threadIdx.x;
    __shared__ float gs[64], zs[64];
    gs[l] = pooled[(size_t)g * 64 + l];
    __syncthreads();
    float z = bl1[l];
    for (int k = 0; k < 64; ++k) z = fmaf(gs[k], Wl1[k * 64 + l], z);
    z = fmaxf(z, 0.f);
    float sum = z;
    #pragma unroll
    for (int off = 32; off; off >>= 1) sum += __shfl_xor(sum, off);
    float mu = sum * (1.f / 64.f);
    float d  = z - mu;
    float vs = d * d;
    #pragma unroll
    for (int off = 32; off; off >>= 1) vs += __shfl_xor(vs, off);
    float var = vs * (1.f / 64.f);
    z = d * rsqrtf(var + 1e-5f) * lng[l] + lnb[l];
    zs[l] = z;
    __syncthreads();
    if (l < 16) {
        float o = bl2[l];
        for (int k = 0; k < 64; ++k) o = fmaf(zs[k], Wl2[k * 16 + l], o);
        out[g * 16 + l] = o;
    }
}

__global__ void copy_ea_kernel(const float* __restrict__ ea, float* __restrict__ out)
{
    for (int i = blockIdx.x * blockDim.x + threadIdx.x; i < N_EDGES; i += gridDim.x * blockDim.x)
        out[i] = ea[i];
}

// ---------------- launch ----------------

extern "C" void kernel_launch(void* const* d_in, const int* in_sizes, int n_in,
                              void* d_out, int out_size, void* d_ws, size_t ws_size,
                              hipStream_t stream)
{
    const float* x    = (const float*)d_in[0];
    const int*   ei   = (const int*)d_in[1];
    const float* ea   = (const float*)d_in[2];
    const int*   bidx = (const int*)d_in[3];
    const float* W1   = (const float*)d_in[4];
    const float* as1  = (const float*)d_in[5];
    const float* ad1  = (const float*)d_in[6];
    const float* We1  = (const float*)d_in[7];
    const float* ae1  = (const float*)d_in[8];
    const float* b1   = (const float*)d_in[9];
    const float* W2   = (const float*)d_in[10];
    const float* as2  = (const float*)d_in[11];
    const float* ad2  = (const float*)d_in[12];
    const float* We2  = (const float*)d_in[13];
    const float* ae2  = (const float*)d_in[14];
    const float* b2   = (const float*)d_in[15];
    const float* Wl1  = (const float*)d_in[16];
    const float* bl1  = (const float*)d_in[17];
    const float* lng  = (const float*)d_in[18];
    const float* lnb  = (const float*)d_in[19];
    const float* Wl2  = (const float*)d_in[20];
    const float* bl2  = (const float*)d_in[21];
    float* out = (float*)d_out;

    char* w = (char*)d_ws;
    float* scalars  = (float*)(w + 0);            // 64 B
    int*   deg      = (int*)  (w + 64);           // 200000 B
    const size_t zbytes = 200064;
    int*   rowstart = (int*)  (w + 200064);       // 200004 B (pad to 400128)
    int*   cursor   = (int*)  (w + 400128);       // 200000 B
    int*   gstart   = (int*)  (w + 600128);       // 516 B (pad to 600704)
    int*   csr_src  = (int*)  (w + 600704);       // 6.6 MB
    float* csr_ea   = (float*)(w + 7200704);      // 6.6 MB
    float* asrc1    = (float*)(w + 13800704);     // 800 KB
    float* adst1    = (float*)(w + 14600704);     // 800 KB
    float* asrc2    = (float*)(w + 15400704);     // 200 KB
    float* adst2    = (float*)(w + 15600704);     // 200 KB
    float* pooled   = (float*)(w + 15800704);     // 32 KB -> 15833472
    unsigned short* W1t  = (unsigned short*)(w + 15833472);   // 64 KB -> 15899008
    unsigned short* W2t  = (unsigned short*)(w + 15899008);   // 32 KB -> 15931776
    unsigned short* h1bf = (unsigned short*)(w + 15931776);   // N_PAD*256*2 = 25624576 -> 41556352
    unsigned short* h1rbf= (unsigned short*)(w + 41556352);   // 25624576 -> 67180928
    unsigned short* h2bf = (unsigned short*)(w + 67180928);   // N_PAD*64*2 = 6406144 -> 73587072
    float* h2out    = (float*)(w + 73587072);     // 12.8 MB -> 86387072

    hipMemsetAsync(d_ws, 0, zbytes, stream);
    ea_sum_kernel<<<512, 256, 0, stream>>>(ea, scalars, N_EDGES);
    scalars_kernel<<<1, 64, 0, stream>>>(scalars, We1, ae1, We2, ae2);
    deg_kernel<<<1024, 256, 0, stream>>>(ei, deg);
    scan_kernel<<<1, 1024, 0, stream>>>(deg, rowstart, cursor);
    fill_kernel<<<1024, 256, 0, stream>>>(ei, ea, scalars, cursor, csr_src, csr_ea);
    gstart_kernel<<<1, 192, 0, stream>>>(bidx, gstart);
    wcast_kernel<<<128, 256, 0, stream>>>(W1, W2, W1t, W2t);

    gemm_mfma<128, 16, true><<<N_PAD / 64, 256, 0, stream>>>(x, W1t, h1bf, N_NODES);
    alphas1_kernel<<<12500, 256, 0, stream>>>(h1bf, as1, ad1, asrc1, adst1);
    agg1_kernel<<<12500, 256, 0, stream>>>(rowstart, csr_src, csr_ea, asrc1, adst1,
                                           scalars, h1bf, b1, h1rbf);
    gemm_mfma<256, 4, false><<<N_PAD / 64, 256, 0, stream>>>(h1rbf, W2t, h2bf, N_NODES);
    alphas2_kernel<<<12500, 256, 0, stream>>>(h2bf, as2, ad2, asrc2, adst2);
    agg2_kernel<<<12500, 256, 0, stream>>>(rowstart, csr_src, csr_ea, asrc2, adst2,
                                           scalars, h2bf, b2, h2out);
    pool_kernel<<<G_GRAPHS, 256, 0, stream>>>(h2out, gstart, pooled);
    mlp_kernel<<<G_GRAPHS, 64, 0, stream>>>(pooled, Wl1, bl1, lng, lnb, Wl2, bl2, out);
    copy_ea_kernel<<<2048, 256, 0, stream>>>(ea, out + 2048);
}

// Round 9
// 703.292 us; speedup vs baseline: 1.3011x; 1.0968x over previous
//
#include <hip/hip_runtime.h>
#include <hip/hip_bf16.h>

#define N_NODES 50000
#define N_PAD 50048           // padded rows for MFMA tiles (multiple of 64)
#define N_EDGES 1600000
#define ET (N_EDGES + N_NODES)
#define G_GRAPHS 128
#define LOG2E 1.4426950408889634f

typedef unsigned short ushort8v __attribute__((ext_vector_type(8)));
typedef unsigned short ushort4v __attribute__((ext_vector_type(4)));
typedef short bf16x8 __attribute__((ext_vector_type(8)));
typedef float f32x4 __attribute__((ext_vector_type(4)));

__device__ __forceinline__ float bf2f(unsigned short u)
{
    return __uint_as_float(((unsigned int)u) << 16);
}
__device__ __forceinline__ unsigned short f2bf(float f)
{
    unsigned int u = __float_as_uint(f);
    u = (u + 0x7FFFu + ((u >> 16) & 1u)) >> 16;
    return (unsigned short)u;
}
__device__ __forceinline__ float exp2fast(float x) { return __builtin_amdgcn_exp2f(x); }
__device__ __forceinline__ float lrelu(float x) { return fmaxf(x, 0.2f * x); }

// ---------------- small utility kernels ----------------

__global__ void ea_sum_kernel(const float* __restrict__ ea, float* __restrict__ out, int n)
{
    float s = 0.f;
    for (int i = blockIdx.x * blockDim.x + threadIdx.x; i < n; i += gridDim.x * blockDim.x)
        s += ea[i];
    #pragma unroll
    for (int off = 32; off; off >>= 1) s += __shfl_xor(s, off);
    if ((threadIdx.x & 63) == 0) atomicAdd(out, s);
}

// ws scalars layout: [0]=ea_sum [1]=ea_mean [2..5]=c1[4]*log2e [6]=c2*log2e
__global__ void scalars_kernel(float* __restrict__ ws,
                               const float* __restrict__ We1, const float* __restrict__ ae1,
                               const float* __restrict__ We2, const float* __restrict__ ae2)
{
    if (threadIdx.x == 0 && blockIdx.x == 0) {
        ws[1] = ws[0] / (float)N_EDGES;
        for (int h = 0; h < 4; ++h) {
            float c = 0.f;
            for (int o = 0; o < 64; ++o) c += We1[h * 64 + o] * ae1[h * 64 + o];
            ws[2 + h] = c * LOG2E;
        }
        float c2 = 0.f;
        for (int o = 0; o < 64; ++o) c2 += We2[o] * ae2[o];
        ws[6] = c2 * LOG2E;
    }
}

__global__ void deg_kernel(const int* __restrict__ ei, int* __restrict__ deg)
{
    for (int e = blockIdx.x * blockDim.x + threadIdx.x; e < ET; e += gridDim.x * blockDim.x) {
        int dst = (e < N_EDGES) ? ei[N_EDGES + e] : (e - N_EDGES);
        atomicAdd(&deg[dst], 1);
    }
}

__global__ __launch_bounds__(1024) void scan_kernel(const int* __restrict__ deg,
                                                    int* __restrict__ rowstart,
                                                    int* __restrict__ cursor)
{
    __shared__ int ssum[1024];
    const int C = (N_NODES + 1023) / 1024;   // 49
    int tid = threadIdx.x;
    int c0 = tid * C, c1 = min(c0 + C, N_NODES);
    int s = 0;
    for (int i = c0; i < c1; ++i) s += deg[i];
    ssum[tid] = s;
    __syncthreads();
    for (int off = 1; off < 1024; off <<= 1) {
        int v = (tid >= off) ? ssum[tid - off] : 0;
        __syncthreads();
        ssum[tid] += v;
        __syncthreads();
    }
    int run = ssum[tid] - s;  // exclusive prefix
    for (int i = c0; i < c1; ++i) { rowstart[i] = run; cursor[i] = run; run += deg[i]; }
    if (tid == 1023) rowstart[N_NODES] = ET;
}

__global__ void fill_kernel(const int* __restrict__ ei, const float* __restrict__ ea,
                            const float* __restrict__ ws, int* __restrict__ cursor,
                            int* __restrict__ csr_src, float* __restrict__ csr_ea)
{
    float mean = ws[1];
    for (int e = blockIdx.x * blockDim.x + threadIdx.x; e < ET; e += gridDim.x * blockDim.x) {
        int src, dst; float v;
        if (e < N_EDGES) { src = ei[e]; dst = ei[N_EDGES + e]; v = ea[e]; }
        else             { src = dst = e - N_EDGES; v = mean; }
        int pos = atomicAdd(&cursor[dst], 1);
        csr_src[pos] = src;
        csr_ea[pos]  = v;
    }
}

// graph start offsets in the sorted batch_idx (129 entries)
__global__ void gstart_kernel(const int* __restrict__ bidx, int* __restrict__ gstart)
{
    int g = blockIdx.x * blockDim.x + threadIdx.x;
    if (g > G_GRAPHS) return;
    int lo = 0, hi = N_NODES;
    while (lo < hi) { int mid = (lo + hi) >> 1; if (bidx[mid] < g) lo = mid + 1; else hi = mid; }
    gstart[g] = lo;
}

// transpose+cast weights: W1[128][256]->W1t[256][128] bf16; W2[256][64]->W2t[64][256] bf16
__global__ void wcast_kernel(const float* __restrict__ W1, const float* __restrict__ W2,
                             unsigned short* __restrict__ W1t, unsigned short* __restrict__ W2t)
{
    int i = blockIdx.x * blockDim.x + threadIdx.x;
    if (i < 128 * 256) { int k = i >> 8, c = i & 255; W1t[c * 128 + k] = f2bf(W1[i]); }
    if (i < 256 * 64)  { int k = i >> 6, c = i & 63;  W2t[c * 256 + k] = f2bf(W2[i]); }
}

// ---------------- MFMA bf16 GEMM + fused alpha projections ----------------
// C[M,NC](bf16) = A[M,K] @ Wt^T; Wt is NC x K (pre-transposed).
// D^T-form: mfma(A'=Wt-frag, B'=A-frag) -> D'[nc,m]; lane (l16,lk) holds row m=base+l16,
// cols cb*16+lk*4+j. Epilogue computes asrc/adst = h . a_s/a_d per head (head = cb>>2
// for NHEADS=4, 0 for NHEADS=1), reduced across lk lanes via shfl_xor(16/32).
template <int K, int NCB, bool A_F32, int NHEADS>
__global__ __launch_bounds__(256) void gemm_mfma(const void* __restrict__ Av,
                                                 const unsigned short* __restrict__ Wt,
                                                 unsigned short* __restrict__ C,
                                                 const float* __restrict__ a_s,
                                                 const float* __restrict__ a_d,
                                                 float* __restrict__ asrc,
                                                 float* __restrict__ adst,
                                                 int M)
{
    const int NC = NCB * 16;
    int wave = threadIdx.x >> 6, lane = threadIdx.x & 63;
    int l16 = lane & 15, lk = lane >> 4;
    int m = blockIdx.x * 64 + wave * 16 + l16;
    if (m >= M) m = M - 1;                 // clamp: tail lanes duplicate row M-1 (benign)
    f32x4 acc[NCB] = {};
    #pragma unroll
    for (int k0 = 0; k0 < K; k0 += 32) {
        int kk = k0 + lk * 8;
        bf16x8 af;
        if constexpr (A_F32) {
            const float* A = (const float*)Av;
            float4 u0 = *(const float4*)&A[(size_t)m * K + kk];
            float4 u1 = *(const float4*)&A[(size_t)m * K + kk + 4];
            af[0] = (short)f2bf(u0.x); af[1] = (short)f2bf(u0.y);
            af[2] = (short)f2bf(u0.z); af[3] = (short)f2bf(u0.w);
            af[4] = (short)f2bf(u1.x); af[5] = (short)f2bf(u1.y);
            af[6] = (short)f2bf(u1.z); af[7] = (short)f2bf(u1.w);
        } else {
            af = *(const bf16x8*)&((const unsigned short*)Av)[(size_t)m * K + kk];
        }
        #pragma unroll
        for (int cb = 0; cb < NCB; ++cb) {
            bf16x8 wf = *(const bf16x8*)&Wt[(size_t)(cb * 16 + l16) * K + kk];
            acc[cb] = __builtin_amdgcn_mfma_f32_16x16x32_bf16(wf, af, acc[cb], 0, 0, 0);
        }
    }
    float sa[NHEADS], da[NHEADS];
    #pragma unroll
    for (int h = 0; h < NHEADS; ++h) { sa[h] = 0.f; da[h] = 0.f; }
    #pragma unroll
    for (int cb = 0; cb < NCB; ++cb) {
        const int hh = (NHEADS == 4) ? (cb >> 2) : 0;
        ushort4v o;
        #pragma unroll
        for (int j = 0; j < 4; ++j) {
            o[j] = f2bf(acc[cb][j]);
            float v = bf2f(o[j]);           // use rounded value (matches gather path)
            int c = cb * 16 + lk * 4 + j;
            sa[hh] = fmaf(v, a_s[c], sa[hh]);
            da[hh] = fmaf(v, a_d[c], da[hh]);
        }
        *(ushort4v*)&C[(size_t)m * NC + cb * 16 + lk * 4] = o;
    }
    #pragma unroll
    for (int h = 0; h < NHEADS; ++h) {
        sa[h] += __shfl_xor(sa[h], 16); sa[h] += __shfl_xor(sa[h], 32);
        da[h] += __shfl_xor(da[h], 16); da[h] += __shfl_xor(da[h], 32);
    }
    if (lk == 0) {
        if constexpr (NHEADS == 4) {
            float4 vs = make_float4(sa[0] * LOG2E, sa[1] * LOG2E, sa[2] * LOG2E, sa[3] * LOG2E);
            float4 vd = make_float4(da[0] * LOG2E, da[1] * LOG2E, da[2] * LOG2E, da[3] * LOG2E);
            *(float4*)&asrc[(size_t)m * 4] = vs;
            *(float4*)&adst[(size_t)m * 4] = vd;
        } else {
            asrc[m] = sa[0] * LOG2E;
            adst[m] = da[0] * LOG2E;
        }
    }
}

// ---------------- layer 1: single-pass softmax-aggregate (exp2 domain) ----------------
// 2 lane-groups x 32 lanes; lane covers 8 channels; 8 loads = 16 edges/iter.
// Accumulates unnormalized sum + denominator in one pass; scales at the end.

__global__ __launch_bounds__(256) void agg1_kernel(const int* __restrict__ rowstart,
                                                   const int* __restrict__ csr_src,
                                                   const float* __restrict__ csr_ea,
                                                   const float* __restrict__ asrc,
                                                   const float* __restrict__ adst,
                                                   const float* __restrict__ ws,
                                                   const unsigned short* __restrict__ h1bf,
                                                   const float* __restrict__ b1,
                                                   unsigned short* __restrict__ h1rbf)
{
    int wid  = (blockIdx.x * blockDim.x + threadIdx.x) >> 6;
    int lane = threadIdx.x & 63;
    if (wid >= N_NODES) return;
    int rs = rowstart[wid], re = rowstart[wid + 1];
    int g   = lane >> 5;        // edge sub-slot (0..1)
    int sub = lane & 31;        // channel block: channels sub*8 .. sub*8+7
    int hh  = sub >> 3;         // head of this lane's channels
    float ad_s = adst[(size_t)wid * 4 + hh];
    float c_s  = ws[2 + hh];

    float acc[8] = {};
    float sden = 0.f;
    for (int p = rs; p < re; p += 16) {
        #pragma unroll
        for (int k = 0; k < 8; ++k) {
            int pe = p + 2 * k + g;
            bool act = pe < re;
            int idx = act ? pe : re - 1;
            int src  = csr_src[idx];
            float ev = csr_ea[idx];
            ushort8v r = *(const ushort8v*)&h1bf[(size_t)src * 256 + sub * 8];
            float al = lrelu(fmaf(ev, c_s, asrc[(size_t)src * 4 + hh] + ad_s));
            float wgt = act ? exp2fast(al) : 0.f;
            sden += wgt;
            #pragma unroll
            for (int j = 0; j < 8; ++j)
                acc[j] = fmaf(bf2f(r[j]), wgt, acc[j]);
        }
    }
    sden += __shfl_xor(sden, 32);
    #pragma unroll
    for (int j = 0; j < 8; ++j) acc[j] += __shfl_xor(acc[j], 32);
    float inv = 1.0f / (sden + 1e-16f);
    if (g == 0) {
        float4 ba = *(const float4*)&b1[sub * 8];
        float4 bb = *(const float4*)&b1[sub * 8 + 4];
        ushort8v ov;
        ov[0] = f2bf(fmaxf(fmaf(acc[0], inv, ba.x), 0.f));
        ov[1] = f2bf(fmaxf(fmaf(acc[1], inv, ba.y), 0.f));
        ov[2] = f2bf(fmaxf(fmaf(acc[2], inv, ba.z), 0.f));
        ov[3] = f2bf(fmaxf(fmaf(acc[3], inv, ba.w), 0.f));
        ov[4] = f2bf(fmaxf(fmaf(acc[4], inv, bb.x), 0.f));
        ov[5] = f2bf(fmaxf(fmaf(acc[5], inv, bb.y), 0.f));
        ov[6] = f2bf(fmaxf(fmaf(acc[6], inv, bb.z), 0.f));
        ov[7] = f2bf(fmaxf(fmaf(acc[7], inv, bb.w), 0.f));
        *(ushort8v*)&h1rbf[(size_t)wid * 256 + sub * 8] = ov;
    }
}

// ---------------- layer 2 (H=1): single-pass softmax-aggregate, direct store ----------------
// 8 lane-groups x 8 lanes; lane covers 8 channels; 4 loads = 32 edges/iter.

__global__ __launch_bounds__(256) void agg2_kernel(const int* __restrict__ rowstart,
                                                   const int* __restrict__ csr_src,
                                                   const float* __restrict__ csr_ea,
                                                   const float* __restrict__ asrc,
                                                   const float* __restrict__ adst,
                                                   const float* __restrict__ ws,
                                                   const unsigned short* __restrict__ h2bf,
                                                   const float* __restrict__ b2,
                                                   float* __restrict__ h2out)
{
    int wid  = (blockIdx.x * blockDim.x + threadIdx.x) >> 6;
    int lane = threadIdx.x & 63;
    if (wid >= N_NODES) return;
    int rs = rowstart[wid], re = rowstart[wid + 1];
    float c2 = ws[6];
    float ad = adst[wid];
    int g   = lane >> 3;   // edge sub-slot (0..7)
    int sub = lane & 7;    // channel block: channels sub*8 .. sub*8+7
    float acc[8] = {};
    float sden = 0.f;
    for (int p = rs; p < re; p += 32) {
        #pragma unroll
        for (int k = 0; k < 4; ++k) {
            int pe = p + 8 * k + g;
            bool act = pe < re;
            int idx = act ? pe : re - 1;
            int src  = csr_src[idx];
            float ev = csr_ea[idx];
            ushort8v r = *(const ushort8v*)&h2bf[(size_t)src * 64 + sub * 8];
            float al = lrelu(fmaf(ev, c2, asrc[src] + ad));
            float wgt = act ? exp2fast(al) : 0.f;
            sden += wgt;
            #pragma unroll
            for (int j = 0; j < 8; ++j)
                acc[j] = fmaf(bf2f(r[j]), wgt, acc[j]);
        }
    }
    sden += __shfl_xor(sden, 8);
    sden += __shfl_xor(sden, 16);
    sden += __shfl_xor(sden, 32);
    #pragma unroll
    for (int j = 0; j < 8; ++j) {
        acc[j] += __shfl_xor(acc[j], 8);
        acc[j] += __shfl_xor(acc[j], 16);
        acc[j] += __shfl_xor(acc[j], 32);
    }
    float inv = 1.0f / (sden + 1e-16f);
    if (g == 0) {
        float4 ba = *(const float4*)&b2[sub * 8];
        float4 bb = *(const float4*)&b2[sub * 8 + 4];
        float4 o0, o1;
        o0.x = fmaf(acc[0], inv, ba.x); o0.y = fmaf(acc[1], inv, ba.y);
        o0.z = fmaf(acc[2], inv, ba.z); o0.w = fmaf(acc[3], inv, ba.w);
        o1.x = fmaf(acc[4], inv, bb.x); o1.y = fmaf(acc[5], inv, bb.y);
        o1.z = fmaf(acc[6], inv, bb.z); o1.w = fmaf(acc[7], inv, bb.w);
        float* o = h2out + (size_t)wid * 64 + sub * 8;
        *(float4*)&o[0] = o0;
        *(float4*)&o[4] = o1;
    }
}

// ---------------- fused mean pool + MLP head: one block per graph ----------------

__global__ __launch_bounds__(256) void pool_mlp_kernel(const float* __restrict__ h2out,
                                                       const int* __restrict__ gstart,
                                                       const float* __restrict__ Wl1,
                                                       const float* __restrict__ bl1,
                                                       const float* __restrict__ lng,
                                                       const float* __restrict__ lnb,
                                                       const float* __restrict__ Wl2,
                                                       const float* __restrict__ bl2,
                                                       float* __restrict__ out)
{
    __shared__ float sh[4][64];
    __shared__ float gs[64], zs[64];
    int g = blockIdx.x;
    int wv = threadIdx.x >> 6, lane = threadIdx.x & 63;
    int s = gstart[g], e = gstart[g + 1];
    float acc = 0.f;
    for (int n = s + wv; n < e; n += 4)
        acc += h2out[(size_t)n * 64 + lane];
    sh[wv][lane] = acc;
    __syncthreads();
    int l = threadIdx.x;
    if (l < 64) {
        float cnt = fmaxf((float)(e - s), 1.f);
        gs[l] = (sh[0][l] + sh[1][l] + sh[2][l] + sh[3][l]) / cnt;
    }
    __syncthreads();
    if (l < 64) {
        float z = bl1[l];
        for (int k = 0; k < 64; ++k) z = fmaf(gs[k], Wl1[k * 64 + l], z);
        z = fmaxf(z, 0.f);
        float sum = z;
        #pragma unroll
        for (int off = 32; off; off >>= 1) sum += __shfl_xor(sum, off);
        float mu = sum * (1.f / 64.f);
        float d  = z - mu;
        float vs = d * d;
        #pragma unroll
        for (int off = 32; off; off >>= 1) vs += __shfl_xor(vs, off);
        float var = vs * (1.f / 64.f);
        zs[l] = d * rsqrtf(var + 1e-5f) * lng[l] + lnb[l];
    }
    __syncthreads();
    if (l < 16) {
        float o = bl2[l];
        for (int k = 0; k < 64; ++k) o = fmaf(zs[k], Wl2[k * 16 + l], o);
        out[g * 16 + l] = o;
    }
}

__global__ void copy_ea_kernel(const float* __restrict__ ea, float* __restrict__ out)
{
    for (int i = blockIdx.x * blockDim.x + threadIdx.x; i < N_EDGES; i += gridDim.x * blockDim.x)
        out[i] = ea[i];
}

// ---------------- launch ----------------

extern "C" void kernel_launch(void* const* d_in, const int* in_sizes, int n_in,
                              void* d_out, int out_size, void* d_ws, size_t ws_size,
                              hipStream_t stream)
{
    const float* x    = (const float*)d_in[0];
    const int*   ei   = (const int*)d_in[1];
    const float* ea   = (const float*)d_in[2];
    const int*   bidx = (const int*)d_in[3];
    const float* W1   = (const float*)d_in[4];
    const float* as1  = (const float*)d_in[5];
    const float* ad1  = (const float*)d_in[6];
    const float* We1  = (const float*)d_in[7];
    const float* ae1  = (const float*)d_in[8];
    const float* b1   = (const float*)d_in[9];
    const float* W2   = (const float*)d_in[10];
    const float* as2  = (const float*)d_in[11];
    const float* ad2  = (const float*)d_in[12];
    const float* We2  = (const float*)d_in[13];
    const float* ae2  = (const float*)d_in[14];
    const float* b2   = (const float*)d_in[15];
    const float* Wl1  = (const float*)d_in[16];
    const float* bl1  = (const float*)d_in[17];
    const float* lng  = (const float*)d_in[18];
    const float* lnb  = (const float*)d_in[19];
    const float* Wl2  = (const float*)d_in[20];
    const float* bl2  = (const float*)d_in[21];
    float* out = (float*)d_out;

    char* w = (char*)d_ws;
    float* scalars  = (float*)(w + 0);            // 64 B
    int*   deg      = (int*)  (w + 64);           // 200000 B
    const size_t zbytes = 200064;
    int*   rowstart = (int*)  (w + 200064);       // 200004 B (pad to 400128)
    int*   cursor   = (int*)  (w + 400128);       // 200000 B
    int*   gstart   = (int*)  (w + 600128);       // 516 B (pad to 600704)
    int*   csr_src  = (int*)  (w + 600704);       // 6.6 MB
    float* csr_ea   = (float*)(w + 7200704);      // 6.6 MB
    float* asrc1    = (float*)(w + 13800704);     // 800 KB
    float* adst1    = (float*)(w + 14600704);     // 800 KB
    float* asrc2    = (float*)(w + 15400704);     // 200 KB
    float* adst2    = (float*)(w + 15600704);     // 200 KB (-> 15800704)
    unsigned short* W1t  = (unsigned short*)(w + 15833472);   // 64 KB -> 15899008
    unsigned short* W2t  = (unsigned short*)(w + 15899008);   // 32 KB -> 15931776
    unsigned short* h1bf = (unsigned short*)(w + 15931776);   // N_PAD*256*2 -> 41556352
    unsigned short* h1rbf= (unsigned short*)(w + 41556352);   // -> 67180928
    unsigned short* h2bf = (unsigned short*)(w + 67180928);   // N_PAD*64*2 -> 73587072
    float* h2out    = (float*)(w + 73587072);     // 12.8 MB -> 86387072

    hipMemsetAsync(d_ws, 0, zbytes, stream);
    ea_sum_kernel<<<512, 256, 0, stream>>>(ea, scalars, N_EDGES);
    scalars_kernel<<<1, 64, 0, stream>>>(scalars, We1, ae1, We2, ae2);
    deg_kernel<<<1024, 256, 0, stream>>>(ei, deg);
    scan_kernel<<<1, 1024, 0, stream>>>(deg, rowstart, cursor);
    fill_kernel<<<1024, 256, 0, stream>>>(ei, ea, scalars, cursor, csr_src, csr_ea);
    gstart_kernel<<<1, 192, 0, stream>>>(bidx, gstart);
    wcast_kernel<<<128, 256, 0, stream>>>(W1, W2, W1t, W2t);

    gemm_mfma<128, 16, true, 4><<<N_PAD / 64, 256, 0, stream>>>(
        x, W1t, h1bf, as1, ad1, asrc1, adst1, N_NODES);
    agg1_kernel<<<12500, 256, 0, stream>>>(rowstart, csr_src, csr_ea, asrc1, adst1,
                                           scalars, h1bf, b1, h1rbf);
    gemm_mfma<256, 4, false, 1><<<N_PAD / 64, 256, 0, stream>>>(
        h1rbf, W2t, h2bf, as2, ad2, asrc2, adst2, N_NODES);
    agg2_kernel<<<12500, 256, 0, stream>>>(rowstart, csr_src, csr_ea, asrc2, adst2,
                                           scalars, h2bf, b2, h2out);
    pool_mlp_kernel<<<G_GRAPHS, 256, 0, stream>>>(h2out, gstart, Wl1, bl1, lng, lnb,
                                                  Wl2, bl2, out);
    copy_ea_kernel<<<2048, 256, 0, stream>>>(ea, out + 2048);
}

// Round 10
// 695.678 us; speedup vs baseline: 1.3154x; 1.0109x over previous
//
#include <hip/hip_runtime.h>
#include <hip/hip_bf16.h>

#define N_NODES 50000
#define N_PAD 50048           // padded rows for MFMA tiles (multiple of 64)
#define N_EDGES 1600000
#define ET (N_EDGES + N_NODES)
#define G_GRAPHS 128
#define LOG2E 1.4426950408889634f

typedef unsigned short ushort8v __attribute__((ext_vector_type(8)));
typedef unsigned short ushort4v __attribute__((ext_vector_type(4)));
typedef short bf16x8 __attribute__((ext_vector_type(8)));
typedef float f32x4 __attribute__((ext_vector_type(4)));

__device__ __forceinline__ float bf2f(unsigned short u)
{
    return __uint_as_float(((unsigned int)u) << 16);
}
__device__ __forceinline__ unsigned short f2bf(float f)
{
    unsigned int u = __float_as_uint(f);
    u = (u + 0x7FFFu + ((u >> 16) & 1u)) >> 16;
    return (unsigned short)u;
}
__device__ __forceinline__ float exp2fast(float x) { return __builtin_amdgcn_exp2f(x); }
__device__ __forceinline__ float lrelu(float x) { return fmaxf(x, 0.2f * x); }

// ---------------- small utility kernels ----------------

__global__ void ea_sum_kernel(const float* __restrict__ ea, float* __restrict__ out, int n)
{
    float s = 0.f;
    for (int i = blockIdx.x * blockDim.x + threadIdx.x; i < n; i += gridDim.x * blockDim.x)
        s += ea[i];
    #pragma unroll
    for (int off = 32; off; off >>= 1) s += __shfl_xor(s, off);
    if ((threadIdx.x & 63) == 0) atomicAdd(out, s);
}

// ws scalars layout: [0]=ea_sum [1]=ea_mean [2..5]=c1[4]*log2e [6]=c2*log2e
__global__ void scalars_kernel(float* __restrict__ ws,
                               const float* __restrict__ We1, const float* __restrict__ ae1,
                               const float* __restrict__ We2, const float* __restrict__ ae2)
{
    if (threadIdx.x == 0 && blockIdx.x == 0) {
        ws[1] = ws[0] / (float)N_EDGES;
        for (int h = 0; h < 4; ++h) {
            float c = 0.f;
            for (int o = 0; o < 64; ++o) c += We1[h * 64 + o] * ae1[h * 64 + o];
            ws[2 + h] = c * LOG2E;
        }
        float c2 = 0.f;
        for (int o = 0; o < 64; ++o) c2 += We2[o] * ae2[o];
        ws[6] = c2 * LOG2E;
    }
}

__global__ void deg_kernel(const int* __restrict__ ei, int* __restrict__ deg)
{
    int e = blockIdx.x * blockDim.x + threadIdx.x;
    if (e >= ET) return;
    int dst = (e < N_EDGES) ? ei[N_EDGES + e] : (e - N_EDGES);
    atomicAdd(&deg[dst], 1);
}

__global__ __launch_bounds__(1024) void scan_kernel(const int* __restrict__ deg,
                                                    int* __restrict__ rowstart,
                                                    int* __restrict__ cursor)
{
    __shared__ int ssum[1024];
    const int C = (N_NODES + 1023) / 1024;   // 49
    int tid = threadIdx.x;
    int c0 = tid * C, c1 = min(c0 + C, N_NODES);
    int s = 0;
    for (int i = c0; i < c1; ++i) s += deg[i];
    ssum[tid] = s;
    __syncthreads();
    for (int off = 1; off < 1024; off <<= 1) {
        int v = (tid >= off) ? ssum[tid - off] : 0;
        __syncthreads();
        ssum[tid] += v;
        __syncthreads();
    }
    int run = ssum[tid] - s;  // exclusive prefix
    for (int i = c0; i < c1; ++i) { rowstart[i] = run; cursor[i] = run; run += deg[i]; }
    if (tid == 1023) rowstart[N_NODES] = ET;
}

// packed CSR record: .x = src, .y = ea bits — single 8B scatter per edge
__global__ void fill_kernel(const int* __restrict__ ei, const float* __restrict__ ea,
                            const float* __restrict__ ws, int* __restrict__ cursor,
                            uint2* __restrict__ csr)
{
    int e = blockIdx.x * blockDim.x + threadIdx.x;
    if (e >= ET) return;
    int src, dst; float v;
    if (e < N_EDGES) { src = ei[e]; dst = ei[N_EDGES + e]; v = ea[e]; }
    else             { src = dst = e - N_EDGES; v = ws[1]; }
    int pos = atomicAdd(&cursor[dst], 1);
    csr[pos] = make_uint2((unsigned)src, __float_as_uint(v));
}

// graph start offsets in the sorted batch_idx (129 entries)
__global__ void gstart_kernel(const int* __restrict__ bidx, int* __restrict__ gstart)
{
    int g = blockIdx.x * blockDim.x + threadIdx.x;
    if (g > G_GRAPHS) return;
    int lo = 0, hi = N_NODES;
    while (lo < hi) { int mid = (lo + hi) >> 1; if (bidx[mid] < g) lo = mid + 1; else hi = mid; }
    gstart[g] = lo;
}

// transpose+cast weights: W1[128][256]->W1t[256][128] bf16; W2[256][64]->W2t[64][256] bf16
__global__ void wcast_kernel(const float* __restrict__ W1, const float* __restrict__ W2,
                             unsigned short* __restrict__ W1t, unsigned short* __restrict__ W2t)
{
    int i = blockIdx.x * blockDim.x + threadIdx.x;
    if (i < 128 * 256) { int k = i >> 8, c = i & 255; W1t[c * 128 + k] = f2bf(W1[i]); }
    if (i < 256 * 64)  { int k = i >> 6, c = i & 63;  W2t[c * 256 + k] = f2bf(W2[i]); }
}

// ---------------- MFMA bf16 GEMM + fused alpha projections ----------------
template <int K, int NCB, bool A_F32, int NHEADS>
__global__ __launch_bounds__(256) void gemm_mfma(const void* __restrict__ Av,
                                                 const unsigned short* __restrict__ Wt,
                                                 unsigned short* __restrict__ C,
                                                 const float* __restrict__ a_s,
                                                 const float* __restrict__ a_d,
                                                 float* __restrict__ asrc,
                                                 float* __restrict__ adst,
                                                 int M)
{
    const int NC = NCB * 16;
    int wave = threadIdx.x >> 6, lane = threadIdx.x & 63;
    int l16 = lane & 15, lk = lane >> 4;
    int m = blockIdx.x * 64 + wave * 16 + l16;
    if (m >= M) m = M - 1;                 // clamp: tail lanes duplicate row M-1 (benign)
    f32x4 acc[NCB] = {};
    #pragma unroll
    for (int k0 = 0; k0 < K; k0 += 32) {
        int kk = k0 + lk * 8;
        bf16x8 af;
        if constexpr (A_F32) {
            const float* A = (const float*)Av;
            float4 u0 = *(const float4*)&A[(size_t)m * K + kk];
            float4 u1 = *(const float4*)&A[(size_t)m * K + kk + 4];
            af[0] = (short)f2bf(u0.x); af[1] = (short)f2bf(u0.y);
            af[2] = (short)f2bf(u0.z); af[3] = (short)f2bf(u0.w);
            af[4] = (short)f2bf(u1.x); af[5] = (short)f2bf(u1.y);
            af[6] = (short)f2bf(u1.z); af[7] = (short)f2bf(u1.w);
        } else {
            af = *(const bf16x8*)&((const unsigned short*)Av)[(size_t)m * K + kk];
        }
        #pragma unroll
        for (int cb = 0; cb < NCB; ++cb) {
            bf16x8 wf = *(const bf16x8*)&Wt[(size_t)(cb * 16 + l16) * K + kk];
            acc[cb] = __builtin_amdgcn_mfma_f32_16x16x32_bf16(wf, af, acc[cb], 0, 0, 0);
        }
    }
    float sa[NHEADS], da[NHEADS];
    #pragma unroll
    for (int h = 0; h < NHEADS; ++h) { sa[h] = 0.f; da[h] = 0.f; }
    #pragma unroll
    for (int cb = 0; cb < NCB; ++cb) {
        const int hh = (NHEADS == 4) ? (cb >> 2) : 0;
        ushort4v o;
        #pragma unroll
        for (int j = 0; j < 4; ++j) {
            o[j] = f2bf(acc[cb][j]);
            float v = bf2f(o[j]);           // use rounded value (matches gather path)
            int c = cb * 16 + lk * 4 + j;
            sa[hh] = fmaf(v, a_s[c], sa[hh]);
            da[hh] = fmaf(v, a_d[c], da[hh]);
        }
        *(ushort4v*)&C[(size_t)m * NC + cb * 16 + lk * 4] = o;
    }
    #pragma unroll
    for (int h = 0; h < NHEADS; ++h) {
        sa[h] += __shfl_xor(sa[h], 16); sa[h] += __shfl_xor(sa[h], 32);
        da[h] += __shfl_xor(da[h], 16); da[h] += __shfl_xor(da[h], 32);
    }
    if (lk == 0) {
        if constexpr (NHEADS == 4) {
            float4 vs = make_float4(sa[0] * LOG2E, sa[1] * LOG2E, sa[2] * LOG2E, sa[3] * LOG2E);
            float4 vd = make_float4(da[0] * LOG2E, da[1] * LOG2E, da[2] * LOG2E, da[3] * LOG2E);
            *(float4*)&asrc[(size_t)m * 4] = vs;
            *(float4*)&adst[(size_t)m * 4] = vd;
        } else {
            asrc[m] = sa[0] * LOG2E;
            adst[m] = da[0] * LOG2E;
        }
    }
}

// ---------------- layer 1: single-pass softmax-aggregate (exp2 domain) ----------------
// 2 lane-groups x 32 lanes; lane covers 8 channels; 8 loads = 16 edges/iter.

__global__ __launch_bounds__(256) void agg1_kernel(const int* __restrict__ rowstart,
                                                   const uint2* __restrict__ csr,
                                                   const float* __restrict__ asrc,
                                                   const float* __restrict__ adst,
                                                   const float* __restrict__ ws,
                                                   const unsigned short* __restrict__ h1bf,
                                                   const float* __restrict__ b1,
                                                   unsigned short* __restrict__ h1rbf)
{
    int wid  = (blockIdx.x * blockDim.x + threadIdx.x) >> 6;
    int lane = threadIdx.x & 63;
    if (wid >= N_NODES) return;
    int rs = rowstart[wid], re = rowstart[wid + 1];
    int g   = lane >> 5;        // edge sub-slot (0..1)
    int sub = lane & 31;        // channel block: channels sub*8 .. sub*8+7
    int hh  = sub >> 3;         // head of this lane's channels
    float ad_s = adst[(size_t)wid * 4 + hh];
    float c_s  = ws[2 + hh];

    float acc[8] = {};
    float sden = 0.f;
    for (int p = rs; p < re; p += 16) {
        #pragma unroll
        for (int k = 0; k < 8; ++k) {
            int pe = p + 2 * k + g;
            bool act = pe < re;
            int idx = act ? pe : re - 1;
            uint2 q = csr[idx];
            int src  = (int)q.x;
            float ev = __uint_as_float(q.y);
            ushort8v r = *(const ushort8v*)&h1bf[(size_t)src * 256 + sub * 8];
            float al = lrelu(fmaf(ev, c_s, asrc[(size_t)src * 4 + hh] + ad_s));
            float wgt = act ? exp2fast(al) : 0.f;
            sden += wgt;
            #pragma unroll
            for (int j = 0; j < 8; ++j)
                acc[j] = fmaf(bf2f(r[j]), wgt, acc[j]);
        }
    }
    sden += __shfl_xor(sden, 32);
    #pragma unroll
    for (int j = 0; j < 8; ++j) acc[j] += __shfl_xor(acc[j], 32);
    float inv = 1.0f / (sden + 1e-16f);
    if (g == 0) {
        float4 ba = *(const float4*)&b1[sub * 8];
        float4 bb = *(const float4*)&b1[sub * 8 + 4];
        ushort8v ov;
        ov[0] = f2bf(fmaxf(fmaf(acc[0], inv, ba.x), 0.f));
        ov[1] = f2bf(fmaxf(fmaf(acc[1], inv, ba.y), 0.f));
        ov[2] = f2bf(fmaxf(fmaf(acc[2], inv, ba.z), 0.f));
        ov[3] = f2bf(fmaxf(fmaf(acc[3], inv, ba.w), 0.f));
        ov[4] = f2bf(fmaxf(fmaf(acc[4], inv, bb.x), 0.f));
        ov[5] = f2bf(fmaxf(fmaf(acc[5], inv, bb.y), 0.f));
        ov[6] = f2bf(fmaxf(fmaf(acc[6], inv, bb.z), 0.f));
        ov[7] = f2bf(fmaxf(fmaf(acc[7], inv, bb.w), 0.f));
        *(ushort8v*)&h1rbf[(size_t)wid * 256 + sub * 8] = ov;
    }
}

// ---------------- layer 2 (H=1): single-pass softmax-aggregate, direct store ----------------
// 8 lane-groups x 8 lanes; lane covers 8 channels; 4 loads = 32 edges/iter.

__global__ __launch_bounds__(256) void agg2_kernel(const int* __restrict__ rowstart,
                                                   const uint2* __restrict__ csr,
                                                   const float* __restrict__ asrc,
                                                   const float* __restrict__ adst,
                                                   const float* __restrict__ ws,
                                                   const unsigned short* __restrict__ h2bf,
                                                   const float* __restrict__ b2,
                                                   float* __restrict__ h2out)
{
    int wid  = (blockIdx.x * blockDim.x + threadIdx.x) >> 6;
    int lane = threadIdx.x & 63;
    if (wid >= N_NODES) return;
    int rs = rowstart[wid], re = rowstart[wid + 1];
    float c2 = ws[6];
    float ad = adst[wid];
    int g   = lane >> 3;   // edge sub-slot (0..7)
    int sub = lane & 7;    // channel block: channels sub*8 .. sub*8+7
    float acc[8] = {};
    float sden = 0.f;
    for (int p = rs; p < re; p += 32) {
        #pragma unroll
        for (int k = 0; k < 4; ++k) {
            int pe = p + 8 * k + g;
            bool act = pe < re;
            int idx = act ? pe : re - 1;
            uint2 q = csr[idx];
            int src  = (int)q.x;
            float ev = __uint_as_float(q.y);
            ushort8v r = *(const ushort8v*)&h2bf[(size_t)src * 64 + sub * 8];
            float al = lrelu(fmaf(ev, c2, asrc[src] + ad));
            float wgt = act ? exp2fast(al) : 0.f;
            sden += wgt;
            #pragma unroll
            for (int j = 0; j < 8; ++j)
                acc[j] = fmaf(bf2f(r[j]), wgt, acc[j]);
        }
    }
    sden += __shfl_xor(sden, 8);
    sden += __shfl_xor(sden, 16);
    sden += __shfl_xor(sden, 32);
    #pragma unroll
    for (int j = 0; j < 8; ++j) {
        acc[j] += __shfl_xor(acc[j], 8);
        acc[j] += __shfl_xor(acc[j], 16);
        acc[j] += __shfl_xor(acc[j], 32);
    }
    float inv = 1.0f / (sden + 1e-16f);
    if (g == 0) {
        float4 ba = *(const float4*)&b2[sub * 8];
        float4 bb = *(const float4*)&b2[sub * 8 + 4];
        float4 o0, o1;
        o0.x = fmaf(acc[0], inv, ba.x); o0.y = fmaf(acc[1], inv, ba.y);
        o0.z = fmaf(acc[2], inv, ba.z); o0.w = fmaf(acc[3], inv, ba.w);
        o1.x = fmaf(acc[4], inv, bb.x); o1.y = fmaf(acc[5], inv, bb.y);
        o1.z = fmaf(acc[6], inv, bb.z); o1.w = fmaf(acc[7], inv, bb.w);
        float* o = h2out + (size_t)wid * 64 + sub * 8;
        *(float4*)&o[0] = o0;
        *(float4*)&o[4] = o1;
    }
}

// ---------------- fused mean pool + MLP head: one block per graph ----------------

__global__ __launch_bounds__(256) void pool_mlp_kernel(const float* __restrict__ h2out,
                                                       const int* __restrict__ gstart,
                                                       const float* __restrict__ Wl1,
                                                       const float* __restrict__ bl1,
                                                       const float* __restrict__ lng,
                                                       const float* __restrict__ lnb,
                                                       const float* __restrict__ Wl2,
                                                       const float* __restrict__ bl2,
                                                       float* __restrict__ out)
{
    __shared__ float sh[4][64];
    __shared__ float gs[64], zs[64];
    int g = blockIdx.x;
    int wv = threadIdx.x >> 6, lane = threadIdx.x & 63;
    int s = gstart[g], e = gstart[g + 1];
    float acc = 0.f;
    for (int n = s + wv; n < e; n += 4)
        acc += h2out[(size_t)n * 64 + lane];
    sh[wv][lane] = acc;
    __syncthreads();
    int l = threadIdx.x;
    if (l < 64) {
        float cnt = fmaxf((float)(e - s), 1.f);
        gs[l] = (sh[0][l] + sh[1][l] + sh[2][l] + sh[3][l]) / cnt;
    }
    __syncthreads();
    if (l < 64) {
        float z = bl1[l];
        for (int k = 0; k < 64; ++k) z = fmaf(gs[k], Wl1[k * 64 + l], z);
        z = fmaxf(z, 0.f);
        float sum = z;
        #pragma unroll
        for (int off = 32; off; off >>= 1) sum += __shfl_xor(sum, off);
        float mu = sum * (1.f / 64.f);
        float d  = z - mu;
        float vs = d * d;
        #pragma unroll
        for (int off = 32; off; off >>= 1) vs += __shfl_xor(vs, off);
        float var = vs * (1.f / 64.f);
        zs[l] = d * rsqrtf(var + 1e-5f) * lng[l] + lnb[l];
    }
    __syncthreads();
    if (l < 16) {
        float o = bl2[l];
        for (int k = 0; k < 64; ++k) o = fmaf(zs[k], Wl2[k * 16 + l], o);
        out[g * 16 + l] = o;
    }
}

__global__ void copy_ea_kernel(const float* __restrict__ ea, float* __restrict__ out)
{
    for (int i = blockIdx.x * blockDim.x + threadIdx.x; i < N_EDGES; i += gridDim.x * blockDim.x)
        out[i] = ea[i];
}

// ---------------- launch ----------------

extern "C" void kernel_launch(void* const* d_in, const int* in_sizes, int n_in,
                              void* d_out, int out_size, void* d_ws, size_t ws_size,
                              hipStream_t stream)
{
    const float* x    = (const float*)d_in[0];
    const int*   ei   = (const int*)d_in[1];
    const float* ea   = (const float*)d_in[2];
    const int*   bidx = (const int*)d_in[3];
    const float* W1   = (const float*)d_in[4];
    const float* as1  = (const float*)d_in[5];
    const float* ad1  = (const float*)d_in[6];
    const float* We1  = (const float*)d_in[7];
    const float* ae1  = (const float*)d_in[8];
    const float* b1   = (const float*)d_in[9];
    const float* W2   = (const float*)d_in[10];
    const float* as2  = (const float*)d_in[11];
    const float* ad2  = (const float*)d_in[12];
    const float* We2  = (const float*)d_in[13];
    const float* ae2  = (const float*)d_in[14];
    const float* b2   = (const float*)d_in[15];
    const float* Wl1  = (const float*)d_in[16];
    const float* bl1  = (const float*)d_in[17];
    const float* lng  = (const float*)d_in[18];
    const float* lnb  = (const float*)d_in[19];
    const float* Wl2  = (const float*)d_in[20];
    const float* bl2  = (const float*)d_in[21];
    float* out = (float*)d_out;

    char* w = (char*)d_ws;
    float* scalars  = (float*)(w + 0);            // 64 B
    int*   deg      = (int*)  (w + 64);           // 200000 B
    const size_t zbytes = 200064;
    int*   rowstart = (int*)  (w + 200064);       // 200004 B (pad to 400128)
    int*   cursor   = (int*)  (w + 400128);       // 200000 B
    int*   gstart   = (int*)  (w + 600128);       // 516 B (pad to 600704)
    uint2* csr      = (uint2*)(w + 600704);       // 13.2 MB -> 13800704
    float* asrc1    = (float*)(w + 13800704);     // 800 KB
    float* adst1    = (float*)(w + 14600704);     // 800 KB
    float* asrc2    = (float*)(w + 15400704);     // 200 KB
    float* adst2    = (float*)(w + 15600704);     // 200 KB (-> 15800704)
    unsigned short* W1t  = (unsigned short*)(w + 15833472);   // 64 KB -> 15899008
    unsigned short* W2t  = (unsigned short*)(w + 15899008);   // 32 KB -> 15931776
    unsigned short* h1bf = (unsigned short*)(w + 15931776);   // N_PAD*256*2 -> 41556352
    unsigned short* h1rbf= (unsigned short*)(w + 41556352);   // -> 67180928
    unsigned short* h2bf = (unsigned short*)(w + 67180928);   // N_PAD*64*2 -> 73587072
    float* h2out    = (float*)(w + 73587072);     // 12.8 MB -> 86387072

    hipMemsetAsync(d_ws, 0, zbytes, stream);
    ea_sum_kernel<<<512, 256, 0, stream>>>(ea, scalars, N_EDGES);
    scalars_kernel<<<1, 64, 0, stream>>>(scalars, We1, ae1, We2, ae2);
    deg_kernel<<<(ET + 255) / 256, 256, 0, stream>>>(ei, deg);
    scan_kernel<<<1, 1024, 0, stream>>>(deg, rowstart, cursor);
    fill_kernel<<<(ET + 255) / 256, 256, 0, stream>>>(ei, ea, scalars, cursor, csr);
    gstart_kernel<<<1, 192, 0, stream>>>(bidx, gstart);
    wcast_kernel<<<128, 256, 0, stream>>>(W1, W2, W1t, W2t);

    gemm_mfma<128, 16, true, 4><<<N_PAD / 64, 256, 0, stream>>>(
        x, W1t, h1bf, as1, ad1, asrc1, adst1, N_NODES);
    agg1_kernel<<<12500, 256, 0, stream>>>(rowstart, csr, asrc1, adst1,
                                           scalars, h1bf, b1, h1rbf);
    gemm_mfma<256, 4, false, 1><<<N_PAD / 64, 256, 0, stream>>>(
        h1rbf, W2t, h2bf, as2, ad2, asrc2, adst2, N_NODES);
    agg2_kernel<<<12500, 256, 0, stream>>>(rowstart, csr, asrc2, adst2,
                                           scalars, h2bf, b2, h2out);
    pool_mlp_kernel<<<G_GRAPHS, 256, 0, stream>>>(h2out, gstart, Wl1, bl1, lng, lnb,
                                                  Wl2, bl2, out);
    copy_ea_kernel<<<2048, 256, 0, stream>>>(ea, out + 2048);
}